// Round 4
// baseline (518.779 us; speedup 1.0000x reference)
//
#include <hip/hip_runtime.h>

#define S_LEN 512
#define D_DIM 512
#define BATCH 32
#define M_ROWS (BATCH * S_LEN)   // 16384
#define NLAYER 3

typedef unsigned short ushort_t;
typedef __bf16 bf16_t;
typedef bf16_t bf16x8 __attribute__((ext_vector_type(8)));
typedef unsigned short u16x8 __attribute__((ext_vector_type(8)));
typedef float f32x4 __attribute__((ext_vector_type(4)));

typedef const __attribute__((address_space(1))) unsigned int* gptr_t;
typedef __attribute__((address_space(3))) unsigned int* lptr_t;

__device__ __forceinline__ ushort_t f2bf(float f) {
  unsigned u = __float_as_uint(f);
  unsigned r = (u + 0x7fffu + ((u >> 16) & 1u)) >> 16;   // RNE
  return (ushort_t)r;
}

// ---------------------------------------------------------------------------
// Weight prep: w[k][n] fp32 -> wt[n][k] bf16 (B^T layout for the GEMM)
// ---------------------------------------------------------------------------
__global__ __launch_bounds__(256)
void wprep_kernel(const float* __restrict__ fw1, const float* __restrict__ fw2,
                  const float* __restrict__ bw1, const float* __restrict__ bw2,
                  ushort_t* __restrict__ wt1, ushort_t* __restrict__ wt2) {
  int z = blockIdx.z;
  int l = z >> 2, m = z & 3;
  const float* bases[4] = {fw1, fw2, bw1, bw2};
  const float* src = bases[m] + (size_t)l * D_DIM * D_DIM;
  int streamIdx = m >> 1;
  int which = m & 1;
  ushort_t* dst = (which ? wt2 : wt1) + ((size_t)streamIdx * NLAYER + l) * D_DIM * D_DIM;

  __shared__ float tile[32][33];
  int n0 = blockIdx.x * 32, k0 = blockIdx.y * 32;
  int tx = threadIdx.x, ty = threadIdx.y;
#pragma unroll
  for (int i = 0; i < 32; i += 8)
    tile[ty + i][tx] = src[(size_t)(k0 + ty + i) * D_DIM + n0 + tx];
  __syncthreads();
#pragma unroll
  for (int i = 0; i < 32; i += 8)
    dst[(size_t)(n0 + ty + i) * D_DIM + k0 + tx] = f2bf(tile[tx][ty + i]);
}

// ---------------------------------------------------------------------------
// Fused window-conv + LayerNorm. grid (M_ROWS/4, 2), block 256 (1 wave/row).
// Writes ONLY yln bf16 [2][M][512]. Residual recomputed in GEMM2 epilogue.
// ---------------------------------------------------------------------------
__global__ __launch_bounds__(256)
void conv_ln_kernel(const float* __restrict__ srcF, int strideF,
                    const float* __restrict__ srcB, int strideB,
                    const float* __restrict__ padLo, const float* __restrict__ padHi,
                    const float* __restrict__ wF, const float* __restrict__ wB,
                    const float* __restrict__ gF, const float* __restrict__ beF,
                    const float* __restrict__ gB, const float* __restrict__ beB,
                    ushort_t* __restrict__ yln) {
  int z = blockIdx.y;
  int tid = threadIdx.x;
  int lane = tid & 63;
  int rl = tid >> 6;
  int row = blockIdx.x * 4 + rl;
  int t = row & (S_LEN - 1);
  const float* src = z ? srcB : srcF;
  int stride = z ? strideB : strideF;
  const float* wv = z ? wB : wF;
  const float* gv = z ? gB : gF;
  const float* bv = z ? beB : beF;
  int toff = z ? 0 : -3;
  int c0 = lane * 4, c1 = 256 + lane * 4;

  float4 a0 = make_float4(0.f, 0.f, 0.f, 0.f);
  float4 a1 = make_float4(0.f, 0.f, 0.f, 0.f);
#pragma unroll
  for (int k = 0; k < 4; ++k) {
    int tt = t + k + toff;
    const float* rp;
    if (tt < 0)            rp = padLo + (size_t)(tt + 3) * D_DIM;
    else if (tt >= S_LEN)  rp = padHi + (size_t)(tt - S_LEN) * D_DIM;
    else                   rp = src + (size_t)(row + k + toff) * stride;
    float wk = wv[k];
    float4 u0 = *(const float4*)(rp + c0);
    float4 u1 = *(const float4*)(rp + c1);
    a0.x = fmaf(wk, u0.x, a0.x); a0.y = fmaf(wk, u0.y, a0.y);
    a0.z = fmaf(wk, u0.z, a0.z); a0.w = fmaf(wk, u0.w, a0.w);
    a1.x = fmaf(wk, u1.x, a1.x); a1.y = fmaf(wk, u1.y, a1.y);
    a1.z = fmaf(wk, u1.z, a1.z); a1.w = fmaf(wk, u1.w, a1.w);
  }
  float s = a0.x + a0.y + a0.z + a0.w + a1.x + a1.y + a1.z + a1.w;
#pragma unroll
  for (int o = 32; o; o >>= 1) s += __shfl_xor(s, o);
  float mean = s * (1.0f / 512.0f);
  float q = 0.f, dx;
  dx = a0.x - mean; q = fmaf(dx, dx, q);
  dx = a0.y - mean; q = fmaf(dx, dx, q);
  dx = a0.z - mean; q = fmaf(dx, dx, q);
  dx = a0.w - mean; q = fmaf(dx, dx, q);
  dx = a1.x - mean; q = fmaf(dx, dx, q);
  dx = a1.y - mean; q = fmaf(dx, dx, q);
  dx = a1.z - mean; q = fmaf(dx, dx, q);
  dx = a1.w - mean; q = fmaf(dx, dx, q);
#pragma unroll
  for (int o = 32; o; o >>= 1) q += __shfl_xor(q, o);
  float sd = sqrtf(q * (1.0f / 511.0f));
  float inv = 1.0f / (sd + 1e-6f);

  size_t base = ((size_t)z * M_ROWS + row) * D_DIM;
  float4 g0 = *(const float4*)(gv + c0), g1 = *(const float4*)(gv + c1);
  float4 b0 = *(const float4*)(bv + c0), b1 = *(const float4*)(bv + c1);
  ushort_t p0[4], p1[4];
  p0[0] = f2bf(g0.x * ((a0.x - mean) * inv) + b0.x);
  p0[1] = f2bf(g0.y * ((a0.y - mean) * inv) + b0.y);
  p0[2] = f2bf(g0.z * ((a0.z - mean) * inv) + b0.z);
  p0[3] = f2bf(g0.w * ((a0.w - mean) * inv) + b0.w);
  p1[0] = f2bf(g1.x * ((a1.x - mean) * inv) + b1.x);
  p1[1] = f2bf(g1.y * ((a1.y - mean) * inv) + b1.y);
  p1[2] = f2bf(g1.z * ((a1.z - mean) * inv) + b1.z);
  p1[3] = f2bf(g1.w * ((a1.w - mean) * inv) + b1.w);
  *(uint2*)(yln + base + c0) = *(uint2*)p0;
  *(uint2*)(yln + base + c1) = *(uint2*)p1;
}

// ---------------------------------------------------------------------------
// 256x256-tile 8-wave bf16 MFMA GEMM, BK=64, 8-phase schedule (T2+T3/T4+T5),
// K=512 -> 8 K-tiles. Grid 256 (1 block/CU), 512 threads.
// SWAPPED-OPERAND MFMA: acc = mfma(bF, aF, acc) computes C^T in-register.
//   D layout (col=lane&15, row=lq*4+reg) under swap means:
//     lane&15 (lm)  -> output ROW within the 16-row fragment
//     lq*4+reg      -> output COL (4 CONSECUTIVE columns per lane)
//   -> epilogue uses float4/uint2 wide stores and float4 tap loads.
// Group loop is ROLLED (#pragma unroll 1) to keep the K-loop I-footprint
// small (HK-style); inner phases/MFMA remain unrolled.
// Staging schedule and barriers identical to round 3 (verified correct):
//   ph0: A1(g+1)->other  ph1: B1(g+1)->other  ph2: A0(g+2)->cur  ph3: B0(g+2)->cur
//   group end: vmcnt(4) (g<6), vmcnt(0) (g==6), none (g==7).
// ---------------------------------------------------------------------------
#define PHASE_PRE()                                         \
  __builtin_amdgcn_sched_barrier(0);                        \
  __builtin_amdgcn_s_barrier();                             \
  asm volatile("s_waitcnt lgkmcnt(0)" ::: "memory");        \
  __builtin_amdgcn_sched_barrier(0);                        \
  __builtin_amdgcn_s_setprio(1);

#define PHASE_PRE_NOLGKM()                                  \
  __builtin_amdgcn_sched_barrier(0);                        \
  __builtin_amdgcn_s_barrier();                             \
  __builtin_amdgcn_s_setprio(1);

#define PHASE_POST()                                        \
  __builtin_amdgcn_s_setprio(0);                            \
  __builtin_amdgcn_sched_barrier(0);                        \
  __builtin_amdgcn_s_barrier();

#define GROUP_END_CK4()                                     \
  __builtin_amdgcn_s_setprio(0);                            \
  __builtin_amdgcn_sched_barrier(0);                        \
  asm volatile("s_waitcnt vmcnt(4)" ::: "memory");          \
  __builtin_amdgcn_sched_barrier(0);                        \
  __builtin_amdgcn_s_barrier();

#define GROUP_END_CK0()                                     \
  __builtin_amdgcn_s_setprio(0);                            \
  __builtin_amdgcn_sched_barrier(0);                        \
  asm volatile("s_waitcnt vmcnt(0)" ::: "memory");          \
  __builtin_amdgcn_sched_barrier(0);                        \
  __builtin_amdgcn_s_barrier();

#define READ_A(MH)                                                        \
  _Pragma("unroll")                                                       \
  for (int m_ = 0; m_ < 4; ++m_) {                                        \
    _Pragma("unroll")                                                     \
    for (int kk_ = 0; kk_ < 2; ++kk_) {                                   \
      int row_ = ((MH) * 4 + m_) * 32 + wr16lm;                           \
      int idx_ = (row_ * 64 + kk_ * 32 + lq * 8) ^ ((row_ & 7) * 8);      \
      union { u16x8 u; bf16x8 b; } t_;                                    \
      t_.u = *(const u16x8*)&pa[idx_];                                    \
      aF[kk_][m_] = t_.b;                                                 \
    }                                                                     \
  }

#define READ_B(NH)                                                        \
  _Pragma("unroll")                                                       \
  for (int n_ = 0; n_ < 2; ++n_) {                                        \
    _Pragma("unroll")                                                     \
    for (int kk_ = 0; kk_ < 2; ++kk_) {                                   \
      int row_ = ((NH) * 2 + n_) * 64 + wc16lm;                           \
      int idx_ = (row_ * 64 + kk_ * 32 + lq * 8) ^ ((row_ & 7) * 8);      \
      union { u16x8 u; bf16x8 b; } t_;                                    \
      t_.u = *(const u16x8*)&pb[idx_];                                    \
      bF[NH][kk_][n_] = t_.b;                                             \
    }                                                                     \
  }

// SWAPPED operand order: A-operand <- B fragment, B-operand <- A fragment.
#define MFMA16(MH, NH)                                                    \
  _Pragma("unroll")                                                       \
  for (int kk_ = 0; kk_ < 2; ++kk_)                                       \
    _Pragma("unroll")                                                     \
    for (int m_ = 0; m_ < 4; ++m_)                                        \
      _Pragma("unroll")                                                   \
      for (int n_ = 0; n_ < 2; ++n_)                                      \
        acc[(MH) * 4 + m_][(NH) * 2 + n_] =                               \
            __builtin_amdgcn_mfma_f32_16x16x32_bf16(                      \
                bF[NH][kk_][n_], aF[kk_][m_],                             \
                acc[(MH) * 4 + m_][(NH) * 2 + n_], 0, 0, 0);

template <int EPI>
__global__ __launch_bounds__(512, 2)
void gemm256_kernel(const ushort_t* __restrict__ A,
                    const ushort_t* __restrict__ Bt_f, const ushort_t* __restrict__ Bt_b,
                    const float* __restrict__ bias_f, const float* __restrict__ bias_b,
                    ushort_t* __restrict__ Hout,       // (EPI==1)
                    float* __restrict__ Cout,          // (EPI==2)
                    const float* __restrict__ srcF, const float* __restrict__ srcB,
                    int srcStride,
                    const float* __restrict__ padLo, const float* __restrict__ padHi,
                    const float* __restrict__ wF, const float* __restrict__ wB) {
  const int K = 512;
  // XCD-aware swizzle, bijective (256 blocks / 8 XCDs = 32 each)
  int bid = blockIdx.x;
  int G = (bid & 7) * 32 + (bid >> 3);
  int z = G >> 7;
  int t2 = G & 127;
  int mblk = t2 >> 1, nblk = t2 & 1;
  int row0 = mblk * 256, n0 = nblk * 256;

  const ushort_t* Ab = A + (size_t)z * M_ROWS * K + (size_t)row0 * K;
  const ushort_t* Bb = (z ? Bt_b : Bt_f) + (size_t)n0 * K;

  __shared__ __attribute__((aligned(16))) ushort_t As[2][256 * 64];  // 64 KB
  __shared__ __attribute__((aligned(16))) ushort_t Bs[2][256 * 64];  // 64 KB

  int tid = threadIdx.x, lane = tid & 63, wave = tid >> 6;
  int wr = wave >> 2, wc = wave & 3;          // 2 x 4 wave grid
  int lm = lane & 15, lq = lane >> 4;
  int wr16lm = wr * 16 + lm;
  int wc16lm = wc * 16 + lm;

  // stage one half-tile (128 rows x 64 cols) of A or B for K-tile g into dst
  auto STAGE = [&](const ushort_t* src, ushort_t* dstBase, int half, int g) {
#pragma unroll
    for (int u = 0; u < 2; ++u) {
      int ch = u * 512 + tid;
      int r = ch >> 3;
      int cs = ((ch & 7) ^ (r & 7)) * 8;          // pre-swizzled source chunk
      __builtin_amdgcn_global_load_lds(
          (gptr_t)(const void*)(src + (size_t)(half * 128 + r) * 512 + g * 64 + cs),
          (lptr_t)(void*)(dstBase + (half * 128 + r) * 64 + (ch & 7) * 8), 16, 0, 0);
    }
  };

  f32x4 acc[8][4] = {};
  bf16x8 aF[2][4];
  bf16x8 bF[2][2][2];

  // ---- prologue: A0(0) B0(0) A1(0) B1(0) A0(1) B0(1)  (6 halves, 12 loads)
  STAGE(Ab, &As[0][0], 0, 0);
  STAGE(Bb, &Bs[0][0], 0, 0);
  STAGE(Ab, &As[0][0], 1, 0);
  STAGE(Bb, &Bs[0][0], 1, 0);
  STAGE(Ab, &As[1][0], 0, 1);
  STAGE(Bb, &Bs[1][0], 0, 1);
  asm volatile("s_waitcnt vmcnt(4)" ::: "memory");   // K-tile 0 fully resident
  __builtin_amdgcn_sched_barrier(0);
  __builtin_amdgcn_s_barrier();

#pragma unroll 1
  for (int g = 0; g < 8; ++g) {
    const ushort_t* pa = &As[g & 1][0];
    const ushort_t* pb = &Bs[g & 1][0];
    ushort_t* oa = &As[(g & 1) ^ 1][0];
    ushort_t* ob = &Bs[(g & 1) ^ 1][0];
    ushort_t* ca = &As[g & 1][0];
    ushort_t* cb = &Bs[g & 1][0];

    // ---- phase 0: quadrant (mh=0, nh=0); stage A1(g+1) -> other buf
    READ_A(0)
    READ_B(0)
    if (g < 7) STAGE(Ab, oa, 1, g + 1);
    PHASE_PRE()
    MFMA16(0, 0)
    PHASE_POST()

    // ---- phase 1: (0,1); stage B1(g+1) -> other buf
    READ_B(1)
    if (g < 7) STAGE(Bb, ob, 1, g + 1);
    PHASE_PRE()
    MFMA16(0, 1)
    PHASE_POST()

    // ---- phase 2: (1,0); stage A0(g+2) -> current buf (A0 free since ph0)
    READ_A(1)
    if (g < 6) STAGE(Ab, ca, 0, g + 2);
    PHASE_PRE()
    MFMA16(1, 0)
    PHASE_POST()

    // ---- phase 3: (1,1); stage B0(g+2) -> current buf (B0 free since ph0)
    if (g < 6) STAGE(Bb, cb, 0, g + 2);
    PHASE_PRE_NOLGKM()
    MFMA16(1, 1)
    if (g < 6) {
      GROUP_END_CK4()
    } else if (g == 6) {
      GROUP_END_CK0()
    } else {
      PHASE_POST()
    }
  }

  // ---- epilogue (swapped layout): fragment (mf,nf):
  //   row  m  = row0 + (mf*2+wr)*16 + lm            (one row per lane)
  //   cols nc = n0 + (nf*4+wc)*16 + lq*4 + r, r=0..3 (4 consecutive cols)
  const float* bias = z ? bias_b : bias_f;
  if (EPI == 1) {
    ushort_t* Hb = Hout + (size_t)z * M_ROWS * 512;
#pragma unroll
    for (int nf = 0; nf < 4; ++nf) {
      int nc0 = n0 + (nf * 4 + wc) * 16 + lq * 4;
      float4 bv = *(const float4*)(bias + nc0);
#pragma unroll
      for (int mf = 0; mf < 8; ++mf) {
        int m = row0 + (mf * 2 + wr) * 16 + lm;
        ushort_t p[4];
        p[0] = f2bf(fmaxf(acc[mf][nf][0] + bv.x, 0.0f));
        p[1] = f2bf(fmaxf(acc[mf][nf][1] + bv.y, 0.0f));
        p[2] = f2bf(fmaxf(acc[mf][nf][2] + bv.z, 0.0f));
        p[3] = f2bf(fmaxf(acc[mf][nf][3] + bv.w, 0.0f));
        *(uint2*)(Hb + (size_t)m * 512 + nc0) = *(uint2*)p;
      }
    }
  } else {
    const float* src = z ? srcB : srcF;
    const float* wv = z ? wB : wF;
    int toff = z ? 0 : -3;
    float w0 = wv[0], w1 = wv[1], w2 = wv[2], w3 = wv[3];
    float* Cb = Cout + (size_t)z * 512;
#pragma unroll
    for (int mf = 0; mf < 8; ++mf) {
      int m = row0 + (mf * 2 + wr) * 16 + lm;
      int t0 = m & (S_LEN - 1);
      int rb = m - t0;                     // batch start row
      const float* rp[4];
#pragma unroll
      for (int q = 0; q < 4; ++q) {
        int tt = t0 + toff + q;
        rp[q] = (tt < 0)       ? padLo + (size_t)(tt + 3) * D_DIM
              : (tt >= S_LEN)  ? padHi + (size_t)(tt - S_LEN) * D_DIM
                               : src + (size_t)(rb + tt) * srcStride;
      }
#pragma unroll
      for (int nf = 0; nf < 4; ++nf) {
        int nc0 = n0 + (nf * 4 + wc) * 16 + lq * 4;
        float4 bv = *(const float4*)(bias + nc0);
        float4 v0 = *(const float4*)(rp[0] + nc0);
        float4 v1 = *(const float4*)(rp[1] + nc0);
        float4 v2 = *(const float4*)(rp[2] + nc0);
        float4 v3 = *(const float4*)(rp[3] + nc0);
        float4 o;
        o.x = acc[mf][nf][0] + bv.x + (w0 * v0.x + w1 * v1.x + w2 * v2.x + w3 * v3.x);
        o.y = acc[mf][nf][1] + bv.y + (w0 * v0.y + w1 * v1.y + w2 * v2.y + w3 * v3.y);
        o.z = acc[mf][nf][2] + bv.z + (w0 * v0.z + w1 * v1.z + w2 * v2.z + w3 * v3.z);
        o.w = acc[mf][nf][3] + bv.w + (w0 * v0.w + w1 * v1.w + w2 * v2.w + w3 * v3.w);
        *(float4*)(Cb + (size_t)m * 1024 + nc0) = o;
      }
    }
  }
}

// ---------------------------------------------------------------------------
extern "C" void kernel_launch(void* const* d_in, const int* in_sizes, int n_in,
                              void* d_out, int out_size, void* d_ws, size_t ws_size,
                              hipStream_t stream) {
  const float* x        = (const float*)d_in[0];
  const float* fwd_pad  = (const float*)d_in[1];
  const float* bwd_pad  = (const float*)d_in[2];
  const float* fwd_w    = (const float*)d_in[3];
  const float* bwd_w    = (const float*)d_in[4];
  const float* fwd_w1   = (const float*)d_in[5];
  const float* fwd_b1   = (const float*)d_in[6];
  const float* fwd_w2   = (const float*)d_in[7];
  const float* fwd_b2   = (const float*)d_in[8];
  const float* fwd_g    = (const float*)d_in[9];
  const float* fwd_beta = (const float*)d_in[10];
  const float* bwd_w1   = (const float*)d_in[11];
  const float* bwd_b1   = (const float*)d_in[12];
  const float* bwd_w2   = (const float*)d_in[13];
  const float* bwd_b2   = (const float*)d_in[14];
  const float* bwd_g    = (const float*)d_in[15];
  const float* bwd_beta = (const float*)d_in[16];
  float* out = (float*)d_out;

  const size_t WSZ = (size_t)D_DIM * D_DIM;           // 262144
  ushort_t* wt1 = (ushort_t*)d_ws;                    // [2][3][512][512] bf16
  ushort_t* wt2 = wt1 + 2 * NLAYER * WSZ;
  ushort_t* yln = wt2 + 2 * NLAYER * WSZ;             // [2][M][512] bf16
  ushort_t* h   = yln + (size_t)2 * M_ROWS * D_DIM;   // [2][M][512] bf16

  wprep_kernel<<<dim3(16, 16, 12), dim3(32, 8), 0, stream>>>(
      fwd_w1, fwd_w2, bwd_w1, bwd_w2, wt1, wt2);

  for (int l = 0; l < NLAYER; ++l) {
    const float *srcF, *srcB;
    int str;
    if (l == 0) {
      srcF = x; srcB = x; str = 512;
    } else {
      srcF = out + (size_t)(l - 1) * M_ROWS * 1024;
      srcB = srcF + 512;
      str = 1024;
    }
    const float* pLo = fwd_pad + (size_t)l * 3 * D_DIM;
    const float* pHi = bwd_pad + (size_t)l * 3 * D_DIM;

    conv_ln_kernel<<<dim3(M_ROWS / 4, 2), 256, 0, stream>>>(
        srcF, str, srcB, str, pLo, pHi,
        fwd_w + l * 4, bwd_w + l * 4,
        fwd_g + l * D_DIM, fwd_beta + l * D_DIM,
        bwd_g + l * D_DIM, bwd_beta + l * D_DIM,
        yln);

    gemm256_kernel<1><<<256, 512, 0, stream>>>(
        yln, wt1 + (size_t)l * WSZ, wt1 + (size_t)(NLAYER + l) * WSZ,
        fwd_b1 + l * D_DIM, bwd_b1 + l * D_DIM,
        h, nullptr,
        nullptr, nullptr, 0, nullptr, nullptr, nullptr, nullptr);

    gemm256_kernel<2><<<256, 512, 0, stream>>>(
        h, wt2 + (size_t)l * WSZ, wt2 + (size_t)(NLAYER + l) * WSZ,
        fwd_b2 + l * D_DIM, bwd_b2 + l * D_DIM,
        nullptr, out + (size_t)l * M_ROWS * 1024,
        srcF, srcB, str, pLo, pHi,
        fwd_w + l * 4, bwd_w + l * 4);
  }
}

// Round 5
// 488.432 us; speedup vs baseline: 1.0621x; 1.0621x over previous
//
#include <hip/hip_runtime.h>

#define S_LEN 512
#define D_DIM 512
#define BATCH 32
#define M_ROWS (BATCH * S_LEN)   // 16384
#define NLAYER 3

typedef unsigned short ushort_t;
typedef __bf16 bf16_t;
typedef bf16_t bf16x8 __attribute__((ext_vector_type(8)));
typedef unsigned short u16x8 __attribute__((ext_vector_type(8)));
typedef float f32x4 __attribute__((ext_vector_type(4)));

typedef const __attribute__((address_space(1))) unsigned int* gptr_t;
typedef __attribute__((address_space(3))) unsigned int* lptr_t;

__device__ __forceinline__ ushort_t f2bf(float f) {
  unsigned u = __float_as_uint(f);
  unsigned r = (u + 0x7fffu + ((u >> 16) & 1u)) >> 16;   // RNE
  return (ushort_t)r;
}

__device__ __forceinline__ float4 f4fma(float w, float4 u, float4 a) {
  a.x = fmaf(w, u.x, a.x); a.y = fmaf(w, u.y, a.y);
  a.z = fmaf(w, u.z, a.z); a.w = fmaf(w, u.w, a.w);
  return a;
}

// ---------------------------------------------------------------------------
// Weight prep: w[k][n] fp32 -> wt[n][k] bf16 (B^T layout for the GEMM)
// ---------------------------------------------------------------------------
__global__ __launch_bounds__(256)
void wprep_kernel(const float* __restrict__ fw1, const float* __restrict__ fw2,
                  const float* __restrict__ bw1, const float* __restrict__ bw2,
                  ushort_t* __restrict__ wt1, ushort_t* __restrict__ wt2) {
  int z = blockIdx.z;
  int l = z >> 2, m = z & 3;
  const float* bases[4] = {fw1, fw2, bw1, bw2};
  const float* src = bases[m] + (size_t)l * D_DIM * D_DIM;
  int streamIdx = m >> 1;
  int which = m & 1;
  ushort_t* dst = (which ? wt2 : wt1) + ((size_t)streamIdx * NLAYER + l) * D_DIM * D_DIM;

  __shared__ float tile[32][33];
  int n0 = blockIdx.x * 32, k0 = blockIdx.y * 32;
  int tx = threadIdx.x, ty = threadIdx.y;
#pragma unroll
  for (int i = 0; i < 32; i += 8)
    tile[ty + i][tx] = src[(size_t)(k0 + ty + i) * D_DIM + n0 + tx];
  __syncthreads();
#pragma unroll
  for (int i = 0; i < 32; i += 8)
    dst[(size_t)(n0 + ty + i) * D_DIM + k0 + tx] = f2bf(tile[tx][ty + i]);
}

// ---------------------------------------------------------------------------
// Fused window-conv + LayerNorm, v2: 4 rows per WAVE (16 per block).
// grid (M_ROWS/16, 2), block 256.
//  - 7 shared tap rows per wave (rows j..j+3 use taps j..j+3 of q=0..6)
//    -> 14 independent float4 loads in flight (MLP) vs 8 before.
//  - one-pass variance: q = sum(y^2) - 512*mean^2  (no mean->var dependency)
//  - 8 independent shuffle-reduce chains (4 rows x {s,s2}) interleaved
//    through one 6-step xor loop -> reduction latency pipelined.
// Writes ONLY yln bf16 [2][M][512]. Residual recomputed in GEMM2 epilogue.
// ---------------------------------------------------------------------------
__global__ __launch_bounds__(256, 4)
void conv_ln_kernel(const float* __restrict__ srcF, int strideF,
                    const float* __restrict__ srcB, int strideB,
                    const float* __restrict__ padLo, const float* __restrict__ padHi,
                    const float* __restrict__ wF, const float* __restrict__ wB,
                    const float* __restrict__ gF, const float* __restrict__ beF,
                    const float* __restrict__ gB, const float* __restrict__ beB,
                    ushort_t* __restrict__ yln) {
  int z = blockIdx.y;
  int tid = threadIdx.x;
  int lane = tid & 63;
  int wid = tid >> 6;
  int row0 = (blockIdx.x * 4 + wid) * 4;     // 4 consecutive rows per wave
  int t0 = row0 & (S_LEN - 1);               // 0..508, multiple of 4
  const float* src = z ? srcB : srcF;
  int stride = z ? strideB : strideF;
  const float* wv = z ? wB : wF;
  const float* gv = z ? gB : gF;
  const float* bv = z ? beB : beF;
  int toff = z ? 0 : -3;                     // fwd taps [t-3,t], bwd [t,t+3]
  int c0 = lane * 4, c1 = 256 + lane * 4;

  float w0 = wv[0], w1 = wv[1], w2 = wv[2], w3 = wv[3];

  // 7 tap rows q=0..6 (tt = t0+toff+q); only one boundary side per stream.
  float4 u0[7], u1[7];
#pragma unroll
  for (int q = 0; q < 7; ++q) {
    int tt = t0 + toff + q;
    const float* rp;
    if (tt < 0)            rp = padLo + (size_t)(tt + 3) * D_DIM;
    else if (tt >= S_LEN)  rp = padHi + (size_t)(tt - S_LEN) * D_DIM;
    else                   rp = src + (size_t)(row0 + toff + q) * stride;
    u0[q] = *(const float4*)(rp + c0);
    u1[q] = *(const float4*)(rp + c1);
  }

  float4 g0 = *(const float4*)(gv + c0), g1 = *(const float4*)(gv + c1);
  float4 b0 = *(const float4*)(bv + c0), b1 = *(const float4*)(bv + c1);

  // conv: row j uses taps q=j..j+3 with weights w0..w3 (holds for both streams)
  float4 y0[4], y1[4];
#pragma unroll
  for (int j = 0; j < 4; ++j) {
    float4 a = make_float4(0.f, 0.f, 0.f, 0.f);
    a = f4fma(w0, u0[j], a); a = f4fma(w1, u0[j + 1], a);
    a = f4fma(w2, u0[j + 2], a); a = f4fma(w3, u0[j + 3], a);
    y0[j] = a;
    float4 c = make_float4(0.f, 0.f, 0.f, 0.f);
    c = f4fma(w0, u1[j], c); c = f4fma(w1, u1[j + 1], c);
    c = f4fma(w2, u1[j + 2], c); c = f4fma(w3, u1[j + 3], c);
    y1[j] = c;
  }

  // in-lane partials
  float s[4], s2[4];
#pragma unroll
  for (int j = 0; j < 4; ++j) {
    float4 a = y0[j], c = y1[j];
    s[j] = a.x + a.y + a.z + a.w + c.x + c.y + c.z + c.w;
    float t = a.x * a.x;
    t = fmaf(a.y, a.y, t); t = fmaf(a.z, a.z, t); t = fmaf(a.w, a.w, t);
    t = fmaf(c.x, c.x, t); t = fmaf(c.y, c.y, t); t = fmaf(c.z, c.z, t);
    t = fmaf(c.w, c.w, t);
    s2[j] = t;
  }

  // interleaved 64-lane reductions: 8 independent chains
#pragma unroll
  for (int o = 32; o; o >>= 1) {
#pragma unroll
    for (int j = 0; j < 4; ++j) {
      s[j]  += __shfl_xor(s[j],  o);
      s2[j] += __shfl_xor(s2[j], o);
    }
  }

  size_t base = ((size_t)z * M_ROWS + row0) * D_DIM;
#pragma unroll
  for (int j = 0; j < 4; ++j) {
    float mean = s[j] * (1.0f / 512.0f);
    float qv = fmaf(-512.0f * mean, mean, s2[j]);
    qv = fmaxf(qv, 0.0f);
    float sd = sqrtf(qv * (1.0f / 511.0f));
    float inv = 1.0f / (sd + 1e-6f);
    ushort_t p0[4], p1[4];
    p0[0] = f2bf(g0.x * ((y0[j].x - mean) * inv) + b0.x);
    p0[1] = f2bf(g0.y * ((y0[j].y - mean) * inv) + b0.y);
    p0[2] = f2bf(g0.z * ((y0[j].z - mean) * inv) + b0.z);
    p0[3] = f2bf(g0.w * ((y0[j].w - mean) * inv) + b0.w);
    p1[0] = f2bf(g1.x * ((y1[j].x - mean) * inv) + b1.x);
    p1[1] = f2bf(g1.y * ((y1[j].y - mean) * inv) + b1.y);
    p1[2] = f2bf(g1.z * ((y1[j].z - mean) * inv) + b1.z);
    p1[3] = f2bf(g1.w * ((y1[j].w - mean) * inv) + b1.w);
    *(uint2*)(yln + base + (size_t)j * D_DIM + c0) = *(uint2*)p0;
    *(uint2*)(yln + base + (size_t)j * D_DIM + c1) = *(uint2*)p1;
  }
}

// ---------------------------------------------------------------------------
// 256x256-tile 8-wave bf16 MFMA GEMM, BK=64, 8-phase schedule (T2+T3/T4+T5),
// K=512 -> 8 K-tiles. Grid 256 (1 block/CU), 512 threads.
// R3-verbatim (best measured: 490.4 us total). R4's rolled-loop + swapped
// operand bundle regressed (+28 us) and is reverted.
// ---------------------------------------------------------------------------
#define PHASE_PRE()                                         \
  __builtin_amdgcn_sched_barrier(0);                        \
  __builtin_amdgcn_s_barrier();                             \
  asm volatile("s_waitcnt lgkmcnt(0)" ::: "memory");        \
  __builtin_amdgcn_sched_barrier(0);                        \
  __builtin_amdgcn_s_setprio(1);

#define PHASE_PRE_NOLGKM()                                  \
  __builtin_amdgcn_sched_barrier(0);                        \
  __builtin_amdgcn_s_barrier();                             \
  __builtin_amdgcn_s_setprio(1);

#define PHASE_POST()                                        \
  __builtin_amdgcn_s_setprio(0);                            \
  __builtin_amdgcn_sched_barrier(0);                        \
  __builtin_amdgcn_s_barrier();

#define GROUP_END_CK4()                                     \
  __builtin_amdgcn_s_setprio(0);                            \
  __builtin_amdgcn_sched_barrier(0);                        \
  asm volatile("s_waitcnt vmcnt(4)" ::: "memory");          \
  __builtin_amdgcn_sched_barrier(0);                        \
  __builtin_amdgcn_s_barrier();

#define GROUP_END_CK0()                                     \
  __builtin_amdgcn_s_setprio(0);                            \
  __builtin_amdgcn_sched_barrier(0);                        \
  asm volatile("s_waitcnt vmcnt(0)" ::: "memory");          \
  __builtin_amdgcn_sched_barrier(0);                        \
  __builtin_amdgcn_s_barrier();

#define READ_A(MH)                                                        \
  _Pragma("unroll")                                                       \
  for (int m_ = 0; m_ < 4; ++m_) {                                        \
    _Pragma("unroll")                                                     \
    for (int kk_ = 0; kk_ < 2; ++kk_) {                                   \
      int row_ = ((MH) * 4 + m_) * 32 + wr16lm;                           \
      int idx_ = (row_ * 64 + kk_ * 32 + lq * 8) ^ ((row_ & 7) * 8);      \
      union { u16x8 u; bf16x8 b; } t_;                                    \
      t_.u = *(const u16x8*)&pa[idx_];                                    \
      aF[kk_][m_] = t_.b;                                                 \
    }                                                                     \
  }

#define READ_B(NH)                                                        \
  _Pragma("unroll")                                                       \
  for (int n_ = 0; n_ < 2; ++n_) {                                        \
    _Pragma("unroll")                                                     \
    for (int kk_ = 0; kk_ < 2; ++kk_) {                                   \
      int row_ = ((NH) * 2 + n_) * 64 + wc16lm;                           \
      int idx_ = (row_ * 64 + kk_ * 32 + lq * 8) ^ ((row_ & 7) * 8);      \
      union { u16x8 u; bf16x8 b; } t_;                                    \
      t_.u = *(const u16x8*)&pb[idx_];                                    \
      bF[NH][kk_][n_] = t_.b;                                             \
    }                                                                     \
  }

#define MFMA16(MH, NH)                                                    \
  _Pragma("unroll")                                                       \
  for (int kk_ = 0; kk_ < 2; ++kk_)                                       \
    _Pragma("unroll")                                                     \
    for (int m_ = 0; m_ < 4; ++m_)                                        \
      _Pragma("unroll")                                                   \
      for (int n_ = 0; n_ < 2; ++n_)                                      \
        acc[(MH) * 4 + m_][(NH) * 2 + n_] =                               \
            __builtin_amdgcn_mfma_f32_16x16x32_bf16(                      \
                aF[kk_][m_], bF[NH][kk_][n_],                             \
                acc[(MH) * 4 + m_][(NH) * 2 + n_], 0, 0, 0);

template <int EPI>
__global__ __launch_bounds__(512, 2)
void gemm256_kernel(const ushort_t* __restrict__ A,
                    const ushort_t* __restrict__ Bt_f, const ushort_t* __restrict__ Bt_b,
                    const float* __restrict__ bias_f, const float* __restrict__ bias_b,
                    ushort_t* __restrict__ Hout,       // (EPI==1)
                    float* __restrict__ Cout,          // (EPI==2)
                    const float* __restrict__ srcF, const float* __restrict__ srcB,
                    int srcStride,
                    const float* __restrict__ padLo, const float* __restrict__ padHi,
                    const float* __restrict__ wF, const float* __restrict__ wB) {
  const int K = 512;
  // XCD-aware swizzle, bijective (256 blocks / 8 XCDs = 32 each)
  int bid = blockIdx.x;
  int G = (bid & 7) * 32 + (bid >> 3);
  int z = G >> 7;
  int t2 = G & 127;
  int mblk = t2 >> 1, nblk = t2 & 1;
  int row0 = mblk * 256, n0 = nblk * 256;

  const ushort_t* Ab = A + (size_t)z * M_ROWS * K + (size_t)row0 * K;
  const ushort_t* Bb = (z ? Bt_b : Bt_f) + (size_t)n0 * K;

  __shared__ __attribute__((aligned(16))) ushort_t As[2][256 * 64];  // 64 KB
  __shared__ __attribute__((aligned(16))) ushort_t Bs[2][256 * 64];  // 64 KB

  int tid = threadIdx.x, lane = tid & 63, wave = tid >> 6;
  int wr = wave >> 2, wc = wave & 3;          // 2 x 4 wave grid
  int lm = lane & 15, lq = lane >> 4;
  int wr16lm = wr * 16 + lm;
  int wc16lm = wc * 16 + lm;

  // stage one half-tile (128 rows x 64 cols) of A or B for K-tile g into dst
  auto STAGE = [&](const ushort_t* src, ushort_t* dstBase, int half, int g) {
#pragma unroll
    for (int u = 0; u < 2; ++u) {
      int ch = u * 512 + tid;
      int r = ch >> 3;
      int cs = ((ch & 7) ^ (r & 7)) * 8;          // pre-swizzled source chunk
      __builtin_amdgcn_global_load_lds(
          (gptr_t)(const void*)(src + (size_t)(half * 128 + r) * 512 + g * 64 + cs),
          (lptr_t)(void*)(dstBase + (half * 128 + r) * 64 + (ch & 7) * 8), 16, 0, 0);
    }
  };

  f32x4 acc[8][4] = {};
  bf16x8 aF[2][4];
  bf16x8 bF[2][2][2];

  // ---- prologue: A0(0) B0(0) A1(0) B1(0) A0(1) B0(1)  (6 halves, 12 loads)
  STAGE(Ab, &As[0][0], 0, 0);
  STAGE(Bb, &Bs[0][0], 0, 0);
  STAGE(Ab, &As[0][0], 1, 0);
  STAGE(Bb, &Bs[0][0], 1, 0);
  STAGE(Ab, &As[1][0], 0, 1);
  STAGE(Bb, &Bs[1][0], 0, 1);
  asm volatile("s_waitcnt vmcnt(4)" ::: "memory");   // K-tile 0 fully resident
  __builtin_amdgcn_sched_barrier(0);
  __builtin_amdgcn_s_barrier();

#pragma unroll
  for (int g = 0; g < 8; ++g) {
    const ushort_t* pa = &As[g & 1][0];
    const ushort_t* pb = &Bs[g & 1][0];
    ushort_t* oa = &As[(g & 1) ^ 1][0];
    ushort_t* ob = &Bs[(g & 1) ^ 1][0];
    ushort_t* ca = &As[g & 1][0];
    ushort_t* cb = &Bs[g & 1][0];

    // ---- phase 0: quadrant (mh=0, nh=0); stage A1(g+1) -> other buf
    READ_A(0)
    READ_B(0)
    if (g + 1 < 8) STAGE(Ab, oa, 1, g + 1);
    PHASE_PRE()
    MFMA16(0, 0)
    PHASE_POST()

    // ---- phase 1: (0,1); stage B1(g+1) -> other buf
    READ_B(1)
    if (g + 1 < 8) STAGE(Bb, ob, 1, g + 1);
    PHASE_PRE()
    MFMA16(0, 1)
    PHASE_POST()

    // ---- phase 2: (1,0); stage A0(g+2) -> current buf (A0 free since ph0)
    READ_A(1)
    if (g + 2 < 8) STAGE(Ab, ca, 0, g + 2);
    PHASE_PRE()
    MFMA16(1, 0)
    PHASE_POST()

    // ---- phase 3: (1,1); stage B0(g+2) -> current buf (B0 free since ph0)
    if (g + 2 < 8) STAGE(Bb, cb, 0, g + 2);
    PHASE_PRE_NOLGKM()
    MFMA16(1, 1)
    if (g < 6) {
      GROUP_END_CK4()
    } else if (g == 6) {
      GROUP_END_CK0()
    } else {
      PHASE_POST()
    }
  }

  // ---- epilogue. C/D layout: col = lane&15, row = (lane>>4)*4 + reg
  const float* bias = z ? bias_b : bias_f;
  if (EPI == 1) {
    ushort_t* Hb = Hout + (size_t)z * M_ROWS * 512;
#pragma unroll
    for (int mf = 0; mf < 8; ++mf) {
      int mbase = row0 + (mf * 2 + wr) * 16 + lq * 4;
#pragma unroll
      for (int nf = 0; nf < 4; ++nf) {
        int n = n0 + (nf * 4 + wc) * 16 + lm;
        float bvn = bias[n];
#pragma unroll
        for (int r = 0; r < 4; ++r) {
          float v = fmaxf(acc[mf][nf][r] + bvn, 0.0f);
          Hb[(size_t)(mbase + r) * 512 + n] = f2bf(v);
        }
      }
    }
  } else {
    const float* src = z ? srcB : srcF;
    const float* wv = z ? wB : wF;
    int toff = z ? 0 : -3;
    float w0 = wv[0], w1 = wv[1], w2 = wv[2], w3 = wv[3];
    float* Cb = Cout + (size_t)z * 512;
#pragma unroll
    for (int mf = 0; mf < 8; ++mf) {
      int mbase = row0 + (mf * 2 + wr) * 16 + lq * 4;
      int t0 = mbase & (S_LEN - 1);
      int rb = mbase - t0;
      const float* rp[7];
#pragma unroll
      for (int q = 0; q < 7; ++q) {
        int tt = t0 + toff + q;
        rp[q] = (tt < 0)       ? padLo + (size_t)(tt + 3) * D_DIM
              : (tt >= S_LEN)  ? padHi + (size_t)(tt - S_LEN) * D_DIM
                               : src + (size_t)(rb + tt) * srcStride;
      }
#pragma unroll
      for (int nf = 0; nf < 4; ++nf) {
        int n = n0 + (nf * 4 + wc) * 16 + lm;
        float v[7];
#pragma unroll
        for (int q = 0; q < 7; ++q) v[q] = rp[q][n];
        float bvn = bias[n];
#pragma unroll
        for (int r = 0; r < 4; ++r) {
          float y = w0 * v[r] + w1 * v[r + 1] + w2 * v[r + 2] + w3 * v[r + 3];
          Cb[(size_t)(mbase + r) * 1024 + n] = acc[mf][nf][r] + bvn + y;
        }
      }
    }
  }
}

// ---------------------------------------------------------------------------
extern "C" void kernel_launch(void* const* d_in, const int* in_sizes, int n_in,
                              void* d_out, int out_size, void* d_ws, size_t ws_size,
                              hipStream_t stream) {
  const float* x        = (const float*)d_in[0];
  const float* fwd_pad  = (const float*)d_in[1];
  const float* bwd_pad  = (const float*)d_in[2];
  const float* fwd_w    = (const float*)d_in[3];
  const float* bwd_w    = (const float*)d_in[4];
  const float* fwd_w1   = (const float*)d_in[5];
  const float* fwd_b1   = (const float*)d_in[6];
  const float* fwd_w2   = (const float*)d_in[7];
  const float* fwd_b2   = (const float*)d_in[8];
  const float* fwd_g    = (const float*)d_in[9];
  const float* fwd_beta = (const float*)d_in[10];
  const float* bwd_w1   = (const float*)d_in[11];
  const float* bwd_b1   = (const float*)d_in[12];
  const float* bwd_w2   = (const float*)d_in[13];
  const float* bwd_b2   = (const float*)d_in[14];
  const float* bwd_g    = (const float*)d_in[15];
  const float* bwd_beta = (const float*)d_in[16];
  float* out = (float*)d_out;

  const size_t WSZ = (size_t)D_DIM * D_DIM;           // 262144
  ushort_t* wt1 = (ushort_t*)d_ws;                    // [2][3][512][512] bf16
  ushort_t* wt2 = wt1 + 2 * NLAYER * WSZ;
  ushort_t* yln = wt2 + 2 * NLAYER * WSZ;             // [2][M][512] bf16
  ushort_t* h   = yln + (size_t)2 * M_ROWS * D_DIM;   // [2][M][512] bf16

  wprep_kernel<<<dim3(16, 16, 12), dim3(32, 8), 0, stream>>>(
      fwd_w1, fwd_w2, bwd_w1, bwd_w2, wt1, wt2);

  for (int l = 0; l < NLAYER; ++l) {
    const float *srcF, *srcB;
    int str;
    if (l == 0) {
      srcF = x; srcB = x; str = 512;
    } else {
      srcF = out + (size_t)(l - 1) * M_ROWS * 1024;
      srcB = srcF + 512;
      str = 1024;
    }
    const float* pLo = fwd_pad + (size_t)l * 3 * D_DIM;
    const float* pHi = bwd_pad + (size_t)l * 3 * D_DIM;

    conv_ln_kernel<<<dim3(M_ROWS / 16, 2), 256, 0, stream>>>(
        srcF, str, srcB, str, pLo, pHi,
        fwd_w + l * 4, bwd_w + l * 4,
        fwd_g + l * D_DIM, fwd_beta + l * D_DIM,
        bwd_g + l * D_DIM, bwd_beta + l * D_DIM,
        yln);

    gemm256_kernel<1><<<256, 512, 0, stream>>>(
        yln, wt1 + (size_t)l * WSZ, wt1 + (size_t)(NLAYER + l) * WSZ,
        fwd_b1 + l * D_DIM, bwd_b1 + l * D_DIM,
        h, nullptr,
        nullptr, nullptr, 0, nullptr, nullptr, nullptr, nullptr);

    gemm256_kernel<2><<<256, 512, 0, stream>>>(
        h, wt2 + (size_t)l * WSZ, wt2 + (size_t)(NLAYER + l) * WSZ,
        fwd_b2 + l * D_DIM, bwd_b2 + l * D_DIM,
        nullptr, out + (size_t)l * M_ROWS * 1024,
        srcF, srcB, str, pLo, pHi,
        fwd_w + l * 4, bwd_w + l * 4);
  }
}